// Round 11
// baseline (219.738 us; speedup 1.0000x reference)
//
#include <hip/hip_runtime.h>
#include <hip/hip_bf16.h>

// GCNConv: coarse bin (64 tgts/bucket, grouped writes) -> per-bucket LDS
// counting sort to per-node CSR (in place over packed) -> per-node wave gather.
// agg[c] = dinv[c] * ( xs[c] + sum_{e: col[e]==c} xs[row[e]] ),
//   xs[i] = (x@W)[i] * dinv[i],  dinv[i] = rsqrt(1 + indeg(i))
// out = dropout(tanh(agg + b)), JAX partitionable-threefry key (0,42), p_keep=0.9:
//   bits[p] = o0^o1 of threefry((0,42), 0, p); u = bitcast(bits>>9|0x3f800000)-1; keep = u<0.9.
//
// R8 lesson: __shfl sources must be ACTIVE lanes — broadcast loops stay uniform.
// R9 lesson: k_p1 occupancy-starved at 128 blocks; k_xw LDS-pipe bound.
// R10 lesson: register-resident W works (VGPR=124, no spill) but 391 blocks =
//   6 waves/CU starved it (14% occ). Fix: 1563 blocks, 16 rows/wave.
//
// ws (20.0 MB): dinv f32[NN] | xsh bf16[NN*64] | packed u32[NE] |
//               noff u32[NN] | bhist i32[NBUCK] | bstart i32[NBUCK+1] | bcur i32[NBUCK]

#define NN 100000
#define NE 1600000
#define NBUCK 1563
#define P1B 512
#define CHUNK 3125          // P1B * CHUNK == NE
#define STAGE_CAP 2560      // > mean(1024) + 48 sigma; fallback if exceeded

// ---------------- Threefry2x32 (JAX-exact) ----------------
__device__ __forceinline__ unsigned rotl32(unsigned x, int r) {
    return (x << r) | (x >> (32 - r));
}

__device__ __forceinline__ void threefry2x32(unsigned k0, unsigned k1,
                                             unsigned x0, unsigned x1,
                                             unsigned& o0, unsigned& o1) {
    const unsigned ks0 = k0, ks1 = k1, ks2 = k0 ^ k1 ^ 0x1BD11BDAu;
    x0 += ks0; x1 += ks1;
    x0 += x1; x1 = rotl32(x1, 13); x1 ^= x0;
    x0 += x1; x1 = rotl32(x1, 15); x1 ^= x0;
    x0 += x1; x1 = rotl32(x1, 26); x1 ^= x0;
    x0 += x1; x1 = rotl32(x1, 6);  x1 ^= x0;
    x0 += ks1; x1 += ks2 + 1u;
    x0 += x1; x1 = rotl32(x1, 17); x1 ^= x0;
    x0 += x1; x1 = rotl32(x1, 29); x1 ^= x0;
    x0 += x1; x1 = rotl32(x1, 16); x1 ^= x0;
    x0 += x1; x1 = rotl32(x1, 24); x1 ^= x0;
    x0 += ks2; x1 += ks0 + 2u;
    x0 += x1; x1 = rotl32(x1, 13); x1 ^= x0;
    x0 += x1; x1 = rotl32(x1, 15); x1 ^= x0;
    x0 += x1; x1 = rotl32(x1, 26); x1 ^= x0;
    x0 += x1; x1 = rotl32(x1, 6);  x1 ^= x0;
    x0 += ks0; x1 += ks1 + 3u;
    x0 += x1; x1 = rotl32(x1, 17); x1 ^= x0;
    x0 += x1; x1 = rotl32(x1, 29); x1 ^= x0;
    x0 += x1; x1 = rotl32(x1, 16); x1 ^= x0;
    x0 += x1; x1 = rotl32(x1, 24); x1 ^= x0;
    x0 += ks1; x1 += ks2 + 4u;
    x0 += x1; x1 = rotl32(x1, 13); x1 ^= x0;
    x0 += x1; x1 = rotl32(x1, 15); x1 ^= x0;
    x0 += x1; x1 = rotl32(x1, 26); x1 ^= x0;
    x0 += x1; x1 = rotl32(x1, 6);  x1 ^= x0;
    x0 += ks2; x1 += ks0 + 5u;
    o0 = x0; o1 = x1;
}

// ---------------- Kernels ----------------
__global__ __launch_bounds__(256) void k_bhist(const int* __restrict__ ei,
                                               int* __restrict__ bhist) {
    __shared__ int h[NBUCK];
    const int tid = threadIdx.x;
    for (int i = tid; i < NBUCK; i += 256) h[i] = 0;
    __syncthreads();
    const int base = blockIdx.x * CHUNK;
    for (int i = tid; i < CHUNK; i += 256) {
        const unsigned t = (unsigned)ei[NE + base + i];
        if (t < NN) atomicAdd(&h[t >> 6], 1);
    }
    __syncthreads();
    for (int i = tid; i < NBUCK; i += 256) {
        const int v = h[i];
        if (v) atomicAdd(&bhist[i], v);
    }
}

__global__ __launch_bounds__(1024) void k_bscan(const int* __restrict__ bhist,
                                                int* __restrict__ bstart,
                                                int* __restrict__ bcur) {
    __shared__ int s[2048];
    const int t = threadIdx.x;
    const int i0 = t, i1 = t + 1024;
    const int c0 = (i0 < NBUCK) ? bhist[i0] : 0;
    const int c1 = (i1 < NBUCK) ? bhist[i1] : 0;
    s[i0] = c0; s[i1] = c1;
    __syncthreads();
    for (int d = 1; d < 2048; d <<= 1) {
        const int a0 = (i0 >= d) ? s[i0 - d] : 0;
        const int a1 = (i1 >= d) ? s[i1 - d] : 0;
        __syncthreads();
        s[i0] += a0; s[i1] += a1;
        __syncthreads();
    }
    if (i0 < NBUCK) { const int b = s[i0] - c0; bstart[i0] = b; bcur[i0] = b; }
    if (i1 < NBUCK) { const int b = s[i1] - c1; bstart[i1] = b; bcur[i1] = b; }
    if (t == 0) bstart[NBUCK] = NE;
}

__global__ __launch_bounds__(256) void k_p1(const int* __restrict__ ei,
                                            int* __restrict__ bcur,
                                            unsigned* __restrict__ packed) {
    __shared__ int hb[NBUCK];
    __shared__ int lc[NBUCK];
    const int tid = threadIdx.x;
    for (int i = tid; i < NBUCK; i += 256) { hb[i] = 0; lc[i] = 0; }
    __syncthreads();
    const int base = blockIdx.x * CHUNK;
    for (int i = tid; i < CHUNK; i += 256) {
        const unsigned t = (unsigned)ei[NE + base + i];
        if (t < NN) atomicAdd(&hb[t >> 6], 1);
    }
    __syncthreads();
    for (int i = tid; i < NBUCK; i += 256) {
        const int h = hb[i];
        hb[i] = h ? atomicAdd(&bcur[i], h) : 0;
    }
    __syncthreads();
    for (int i = tid; i < CHUNK; i += 256) {
        const unsigned t = (unsigned)ei[NE + base + i];
        if (t >= NN) continue;
        const unsigned src = (unsigned)ei[base + i];
        const int bk = t >> 6;
        const unsigned pos = (unsigned)(hb[bk] + atomicAdd(&lc[bk], 1));
        if (pos < NE) packed[pos] = src | ((t & 63u) << 17);
    }
}

// Per-bucket: tl-histogram -> dinv + noff; LDS-stage + counting-sort the
// segment back over packed (node-grouped, tl stripped). Fallback: scan-mode.
__global__ __launch_bounds__(256) void k_sortb(unsigned* __restrict__ packed,
                                               const int* __restrict__ bstart,
                                               float* __restrict__ dinv,
                                               unsigned* __restrict__ noff) {
    __shared__ unsigned stage[STAGE_CAP];
    __shared__ int hist[64];
    __shared__ int pref[64];
    __shared__ int cur[64];
    const int tid = threadIdx.x;
    const int b = blockIdx.x;
    int s = bstart[b], e = bstart[b + 1];
    if (s < 0) s = 0;
    if (e > NE) e = NE;
    if (e < s) e = s;
    const int seg = e - s;
    if (tid < 64) hist[tid] = 0;
    __syncthreads();
    for (int i = s + tid; i < e; i += 256) atomicAdd(&hist[packed[i] >> 17], 1);
    __syncthreads();
    if (tid == 0) {
        int run = 0;
        for (int t = 0; t < 64; ++t) { pref[t] = run; run += hist[t]; }
    }
    __syncthreads();
    if (tid < 64) cur[tid] = pref[tid];
    const bool oversize = (seg > STAGE_CAP);
    if (tid < 64) {
        const int c = b * 64 + tid;
        if (c < NN) {
            const int deg = hist[tid];
            dinv[c] = rsqrtf(1.0f + (float)deg);
            const unsigned dcap = oversize ? 2047u
                                           : ((deg > 2046) ? 2047u : (unsigned)deg);
            noff[c] = (unsigned)(s + pref[tid]) | (dcap << 21);
        }
    }
    if (oversize) return;  // segment left in src|tl form; k_agg scans it
    __syncthreads();
    for (int i = s + tid; i < e; i += 256) stage[i - s] = packed[i];
    __syncthreads();
    for (int k = tid; k < seg; k += 256) {
        const unsigned pk = stage[k];
        const int tl = (int)(pk >> 17);
        const int pos = s + atomicAdd(&cur[tl], 1);
        packed[pos] = pk & 0x1FFFFu;
    }
}

// x@W with W register-resident (R10 design, TLP-fixed): 1563 blocks, 16 rows
// per wave. wreg loaded once from LDS (lane = output dim; 2 lanes/bank free),
// then per row: 16 broadcast float4 x loads (ILP-16) + 64 register FMAs.
__global__ __launch_bounds__(256) void k_xw(const float* __restrict__ x,
                                            const float* __restrict__ W,
                                            const float* __restrict__ dinv,
                                            __hip_bfloat16* __restrict__ xsh) {
    __shared__ float Wl[64 * 64];
    const int tid = threadIdx.x;
    for (int i = tid; i < 64 * 64; i += 256) Wl[i] = W[i];  // coalesced
    __syncthreads();
    const int wid = tid >> 6, lane = tid & 63;
    float wreg[64];
#pragma unroll
    for (int k = 0; k < 64; ++k) wreg[k] = Wl[k * 64 + lane];  // W^T column -> regs
    const int row0 = blockIdx.x * 64 + wid * 16;  // 16 rows per wave
#pragma unroll 1
    for (int r = 0; r < 16; ++r) {
        const int row = row0 + r;
        if (row >= NN) break;  // uniform per wave
        const float4* __restrict__ xr = (const float4*)(x + (size_t)row * 64);
        float sum = 0.0f;
#pragma unroll
        for (int q = 0; q < 16; ++q) {
            const float4 xv = xr[q];  // wave-uniform broadcast load
            sum = fmaf(xv.x, wreg[4 * q + 0], sum);
            sum = fmaf(xv.y, wreg[4 * q + 1], sum);
            sum = fmaf(xv.z, wreg[4 * q + 2], sum);
            sum = fmaf(xv.w, wreg[4 * q + 3], sum);
        }
        xsh[(size_t)row * 64 + lane] = __float2bfloat16(sum * dinv[row]);
    }
}

// One wave per node, lane = dim. Uniform __shfl broadcast loop, manually
// unrolled x4 into 4 independent accumulator chains (ILP), uniform tail.
// Fused bias + tanh + JAX dropout epilogue; coalesced out writes.
__global__ __launch_bounds__(256) void k_agg(const unsigned* __restrict__ packed,
                                             const unsigned* __restrict__ noff,
                                             const int* __restrict__ bstart,
                                             const __hip_bfloat16* __restrict__ xsh,
                                             const float* __restrict__ dinv,
                                             const float* __restrict__ bias,
                                             float* __restrict__ out) {
    const int tid = threadIdx.x;
    const int c = blockIdx.x * 4 + (tid >> 6);  // grid exact: 25000*4 == NN
    const int lane = tid & 63;
    const unsigned info = noff[c];
    const int off = (int)(info & 0x1FFFFFu);
    const int dcap = (int)(info >> 21);

    float a0 = __bfloat162float(xsh[(size_t)c * 64 + lane]);  // self-loop term
    float a1 = 0.0f, a2 = 0.0f, a3 = 0.0f;
    if (dcap < 2047) {
        for (int base = 0; base < dcap; base += 64) {
            const int m = (dcap - base < 64) ? (dcap - base) : 64;
            const unsigned sv = (lane < m) ? packed[off + base + lane] : 0u;
            int j = 0;
            for (; j + 3 < m; j += 4) {  // uniform trip count, all lanes active
                const int s0 = (int)__shfl(sv, j);
                const int s1 = (int)__shfl(sv, j + 1);
                const int s2 = (int)__shfl(sv, j + 2);
                const int s3 = (int)__shfl(sv, j + 3);
                a0 += __bfloat162float(xsh[(size_t)s0 * 64 + lane]);
                a1 += __bfloat162float(xsh[(size_t)s1 * 64 + lane]);
                a2 += __bfloat162float(xsh[(size_t)s2 * 64 + lane]);
                a3 += __bfloat162float(xsh[(size_t)s3 * 64 + lane]);
            }
            for (; j < m; ++j) {  // uniform tail
                const int s0 = (int)__shfl(sv, j);
                a0 += __bfloat162float(xsh[(size_t)s0 * 64 + lane]);
            }
        }
    } else {  // scan-mode fallback (oversized bucket; segment still src|tl)
        const int b = c >> 6;
        int ss = bstart[b], ee = bstart[b + 1];
        if (ss < 0) ss = 0;
        if (ee > NE) ee = NE;
        const unsigned tl = (unsigned)(c & 63);
        for (int i = ss; i < ee; ++i) {
            const unsigned pk = packed[i];  // uniform address: broadcast load
            if ((pk >> 17) == tl)
                a0 += __bfloat162float(xsh[(size_t)(pk & 0x1FFFFu) * 64 + lane]);
        }
    }
    const float a = (a0 + a1) + (a2 + a3);
    const int p = c * 64 + lane;
    unsigned o0, o1;
    threefry2x32(0u, 42u, 0u, (unsigned)p, o0, o1);
    const unsigned bits = o0 ^ o1;
    const float u = __uint_as_float((bits >> 9) | 0x3f800000u) - 1.0f;
    const float h = tanhf(dinv[c] * a + bias[lane]);
    out[p] = (u < 0.9f) ? h / 0.9f : 0.0f;
}

extern "C" void kernel_launch(void* const* d_in, const int* in_sizes, int n_in,
                              void* d_out, int out_size, void* d_ws, size_t ws_size,
                              hipStream_t stream) {
    const float* x  = (const float*)d_in[0];
    const float* W  = (const float*)d_in[1];
    const float* b  = (const float*)d_in[2];
    const int*   ei = (const int*)d_in[3];
    float* out = (float*)d_out;

    float* dinv = (float*)d_ws;                             // f32[NN]
    __hip_bfloat16* xsh = (__hip_bfloat16*)(dinv + NN);     // bf16[NN*64]
    unsigned* packed = (unsigned*)(xsh + (size_t)NN * 64);  // u32[NE]
    unsigned* noff = packed + NE;                           // u32[NN]
    int* bhist  = (int*)(noff + NN);                        // i32[NBUCK]
    int* bstart = bhist + NBUCK;                            // i32[NBUCK+1]
    int* bcur   = bstart + NBUCK + 1;                       // i32[NBUCK]

    hipMemsetAsync(bhist, 0, NBUCK * sizeof(int), stream);
    k_bhist<<<P1B, 256, 0, stream>>>(ei, bhist);
    k_bscan<<<1, 1024, 0, stream>>>(bhist, bstart, bcur);
    k_p1<<<P1B, 256, 0, stream>>>(ei, bcur, packed);
    k_sortb<<<NBUCK, 256, 0, stream>>>(packed, bstart, dinv, noff);
    k_xw<<<(NN + 63) / 64, 256, 0, stream>>>(x, W, dinv, xsh);
    k_agg<<<NN / 4, 256, 0, stream>>>(packed, noff, bstart, xsh, dinv, b, out);
}

// Round 12
// 189.526 us; speedup vs baseline: 1.1594x; 1.1594x over previous
//
#include <hip/hip_runtime.h>
#include <hip/hip_bf16.h>

// GCNConv: coarse bin (64 tgts/bucket, grouped writes) -> per-bucket LDS
// counting sort to per-node CSR (in place over packed) -> per-node wave gather.
// agg[c] = dinv[c] * ( xs[c] + sum_{e: col[e]==c} xs[row[e]] ),
//   xs[i] = (x@W)[i] * dinv[i],  dinv[i] = rsqrt(1 + indeg(i))
// out = dropout(tanh(agg + b)), JAX partitionable-threefry key (0,42), p_keep=0.9:
//   bits[p] = o0^o1 of threefry((0,42), 0, p); u = bitcast(bits>>9|0x3f800000)-1; keep = u<0.9.
//
// R8: __shfl sources must be ACTIVE lanes — broadcast loops stay uniform.
// R9: k_p1 starved at 128 blocks; k_xw with per-k W ds_reads = LDS-pipe bound (66us).
// R10/R11: wreg works but wave-uniform GLOBAL x loads serialize (no regs for
//   16 in-flight float4 at VGPR=124) -> ~2000cyc/row, TLP can't hide it.
// R12 fix: x staged in LDS; per-row 16 ds_read_b128 BROADCASTS (same-addr =
//   free, m136) + 64 reg FMAs. W stays register-resident.
//
// ws (20.0 MB): dinv f32[NN] | xsh bf16[NN*64] | packed u32[NE] |
//               noff u32[NN] | bhist i32[NBUCK] | bstart i32[NBUCK+1] | bcur i32[NBUCK]

#define NN 100000
#define NE 1600000
#define NBUCK 1563
#define P1B 512
#define CHUNK 3125          // P1B * CHUNK == NE
#define STAGE_CAP 2560      // > mean(1024) + 48 sigma; fallback if exceeded

// ---------------- Threefry2x32 (JAX-exact) ----------------
__device__ __forceinline__ unsigned rotl32(unsigned x, int r) {
    return (x << r) | (x >> (32 - r));
}

__device__ __forceinline__ void threefry2x32(unsigned k0, unsigned k1,
                                             unsigned x0, unsigned x1,
                                             unsigned& o0, unsigned& o1) {
    const unsigned ks0 = k0, ks1 = k1, ks2 = k0 ^ k1 ^ 0x1BD11BDAu;
    x0 += ks0; x1 += ks1;
    x0 += x1; x1 = rotl32(x1, 13); x1 ^= x0;
    x0 += x1; x1 = rotl32(x1, 15); x1 ^= x0;
    x0 += x1; x1 = rotl32(x1, 26); x1 ^= x0;
    x0 += x1; x1 = rotl32(x1, 6);  x1 ^= x0;
    x0 += ks1; x1 += ks2 + 1u;
    x0 += x1; x1 = rotl32(x1, 17); x1 ^= x0;
    x0 += x1; x1 = rotl32(x1, 29); x1 ^= x0;
    x0 += x1; x1 = rotl32(x1, 16); x1 ^= x0;
    x0 += x1; x1 = rotl32(x1, 24); x1 ^= x0;
    x0 += ks2; x1 += ks0 + 2u;
    x0 += x1; x1 = rotl32(x1, 13); x1 ^= x0;
    x0 += x1; x1 = rotl32(x1, 15); x1 ^= x0;
    x0 += x1; x1 = rotl32(x1, 26); x1 ^= x0;
    x0 += x1; x1 = rotl32(x1, 6);  x1 ^= x0;
    x0 += ks0; x1 += ks1 + 3u;
    x0 += x1; x1 = rotl32(x1, 17); x1 ^= x0;
    x0 += x1; x1 = rotl32(x1, 29); x1 ^= x0;
    x0 += x1; x1 = rotl32(x1, 16); x1 ^= x0;
    x0 += x1; x1 = rotl32(x1, 24); x1 ^= x0;
    x0 += ks1; x1 += ks2 + 4u;
    x0 += x1; x1 = rotl32(x1, 13); x1 ^= x0;
    x0 += x1; x1 = rotl32(x1, 15); x1 ^= x0;
    x0 += x1; x1 = rotl32(x1, 26); x1 ^= x0;
    x0 += x1; x1 = rotl32(x1, 6);  x1 ^= x0;
    x0 += ks2; x1 += ks0 + 5u;
    o0 = x0; o1 = x1;
}

// ---------------- Kernels ----------------
__global__ __launch_bounds__(256) void k_bhist(const int* __restrict__ ei,
                                               int* __restrict__ bhist) {
    __shared__ int h[NBUCK];
    const int tid = threadIdx.x;
    for (int i = tid; i < NBUCK; i += 256) h[i] = 0;
    __syncthreads();
    const int base = blockIdx.x * CHUNK;
    for (int i = tid; i < CHUNK; i += 256) {
        const unsigned t = (unsigned)ei[NE + base + i];
        if (t < NN) atomicAdd(&h[t >> 6], 1);
    }
    __syncthreads();
    for (int i = tid; i < NBUCK; i += 256) {
        const int v = h[i];
        if (v) atomicAdd(&bhist[i], v);
    }
}

__global__ __launch_bounds__(1024) void k_bscan(const int* __restrict__ bhist,
                                                int* __restrict__ bstart,
                                                int* __restrict__ bcur) {
    __shared__ int s[2048];
    const int t = threadIdx.x;
    const int i0 = t, i1 = t + 1024;
    const int c0 = (i0 < NBUCK) ? bhist[i0] : 0;
    const int c1 = (i1 < NBUCK) ? bhist[i1] : 0;
    s[i0] = c0; s[i1] = c1;
    __syncthreads();
    for (int d = 1; d < 2048; d <<= 1) {
        const int a0 = (i0 >= d) ? s[i0 - d] : 0;
        const int a1 = (i1 >= d) ? s[i1 - d] : 0;
        __syncthreads();
        s[i0] += a0; s[i1] += a1;
        __syncthreads();
    }
    if (i0 < NBUCK) { const int b = s[i0] - c0; bstart[i0] = b; bcur[i0] = b; }
    if (i1 < NBUCK) { const int b = s[i1] - c1; bstart[i1] = b; bcur[i1] = b; }
    if (t == 0) bstart[NBUCK] = NE;
}

__global__ __launch_bounds__(256) void k_p1(const int* __restrict__ ei,
                                            int* __restrict__ bcur,
                                            unsigned* __restrict__ packed) {
    __shared__ int hb[NBUCK];
    __shared__ int lc[NBUCK];
    const int tid = threadIdx.x;
    for (int i = tid; i < NBUCK; i += 256) { hb[i] = 0; lc[i] = 0; }
    __syncthreads();
    const int base = blockIdx.x * CHUNK;
    for (int i = tid; i < CHUNK; i += 256) {
        const unsigned t = (unsigned)ei[NE + base + i];
        if (t < NN) atomicAdd(&hb[t >> 6], 1);
    }
    __syncthreads();
    for (int i = tid; i < NBUCK; i += 256) {
        const int h = hb[i];
        hb[i] = h ? atomicAdd(&bcur[i], h) : 0;
    }
    __syncthreads();
    for (int i = tid; i < CHUNK; i += 256) {
        const unsigned t = (unsigned)ei[NE + base + i];
        if (t >= NN) continue;
        const unsigned src = (unsigned)ei[base + i];
        const int bk = t >> 6;
        const unsigned pos = (unsigned)(hb[bk] + atomicAdd(&lc[bk], 1));
        if (pos < NE) packed[pos] = src | ((t & 63u) << 17);
    }
}

// Per-bucket: tl-histogram -> dinv + noff; LDS-stage + counting-sort the
// segment back over packed (node-grouped, tl stripped). Fallback: scan-mode.
__global__ __launch_bounds__(256) void k_sortb(unsigned* __restrict__ packed,
                                               const int* __restrict__ bstart,
                                               float* __restrict__ dinv,
                                               unsigned* __restrict__ noff) {
    __shared__ unsigned stage[STAGE_CAP];
    __shared__ int hist[64];
    __shared__ int pref[64];
    __shared__ int cur[64];
    const int tid = threadIdx.x;
    const int b = blockIdx.x;
    int s = bstart[b], e = bstart[b + 1];
    if (s < 0) s = 0;
    if (e > NE) e = NE;
    if (e < s) e = s;
    const int seg = e - s;
    if (tid < 64) hist[tid] = 0;
    __syncthreads();
    for (int i = s + tid; i < e; i += 256) atomicAdd(&hist[packed[i] >> 17], 1);
    __syncthreads();
    if (tid == 0) {
        int run = 0;
        for (int t = 0; t < 64; ++t) { pref[t] = run; run += hist[t]; }
    }
    __syncthreads();
    if (tid < 64) cur[tid] = pref[tid];
    const bool oversize = (seg > STAGE_CAP);
    if (tid < 64) {
        const int c = b * 64 + tid;
        if (c < NN) {
            const int deg = hist[tid];
            dinv[c] = rsqrtf(1.0f + (float)deg);
            const unsigned dcap = oversize ? 2047u
                                           : ((deg > 2046) ? 2047u : (unsigned)deg);
            noff[c] = (unsigned)(s + pref[tid]) | (dcap << 21);
        }
    }
    if (oversize) return;  // segment left in src|tl form; k_agg scans it
    __syncthreads();
    for (int i = s + tid; i < e; i += 256) stage[i - s] = packed[i];
    __syncthreads();
    for (int k = tid; k < seg; k += 256) {
        const unsigned pk = stage[k];
        const int tl = (int)(pk >> 17);
        const int pos = s + atomicAdd(&cur[tl], 1);
        packed[pos] = pk & 0x1FFFFu;
    }
}

// x@W: W register-resident (from LDS-staged Wl), x rows staged in LDS and
// distributed per-row via 16 ds_read_b128 BROADCASTS (same address across the
// wave = conflict-free broadcast) + 64 register FMAs. 64 rows/block, 16/wave.
__global__ __launch_bounds__(256) void k_xw(const float* __restrict__ x,
                                            const float* __restrict__ W,
                                            const float* __restrict__ dinv,
                                            __hip_bfloat16* __restrict__ xsh) {
    __shared__ float Wl[64 * 64];   // 16 KB
    __shared__ float xl[64 * 64];   // 16 KB: this block's 64 x-rows
    const int tid = threadIdx.x;
    for (int i = tid; i < 64 * 64; i += 256) Wl[i] = W[i];  // coalesced
    const int row0 = blockIdx.x * 64;
    {   // stage x rows (guard last block: 64*1563 > NN)
        const int nfl4 = ((NN - row0) < 64 ? (NN - row0) : 64) * 16;  // float4 count
        const float4* __restrict__ xg = (const float4*)(x + (size_t)row0 * 64);
        float4* __restrict__ xl4 = (float4*)xl;
        for (int i = tid; i < nfl4; i += 256) xl4[i] = xg[i];
    }
    __syncthreads();
    const int wid = tid >> 6, lane = tid & 63;
    float wreg[64];
#pragma unroll
    for (int k = 0; k < 64; ++k) wreg[k] = Wl[k * 64 + lane];  // W^T col -> regs
    const int rbase = wid * 16;
#pragma unroll 1
    for (int r = 0; r < 16; ++r) {
        const int row = row0 + rbase + r;
        if (row >= NN) break;  // wave-uniform
        const float4* __restrict__ xr4 = (const float4*)(xl + (rbase + r) * 64);
        float sum = 0.0f;
#pragma unroll
        for (int q = 0; q < 16; ++q) {
            const float4 xv = xr4[q];  // ds_read_b128 broadcast (same addr)
            sum = fmaf(xv.x, wreg[4 * q + 0], sum);
            sum = fmaf(xv.y, wreg[4 * q + 1], sum);
            sum = fmaf(xv.z, wreg[4 * q + 2], sum);
            sum = fmaf(xv.w, wreg[4 * q + 3], sum);
        }
        xsh[(size_t)row * 64 + lane] = __float2bfloat16(sum * dinv[row]);
    }
}

// One wave per node, lane = dim. Uniform __shfl broadcast loop, manually
// unrolled x4 into 4 independent accumulator chains (ILP), uniform tail.
// Fused bias + tanh + JAX dropout epilogue; coalesced out writes.
__global__ __launch_bounds__(256) void k_agg(const unsigned* __restrict__ packed,
                                             const unsigned* __restrict__ noff,
                                             const int* __restrict__ bstart,
                                             const __hip_bfloat16* __restrict__ xsh,
                                             const float* __restrict__ dinv,
                                             const float* __restrict__ bias,
                                             float* __restrict__ out) {
    const int tid = threadIdx.x;
    const int c = blockIdx.x * 4 + (tid >> 6);  // grid exact: 25000*4 == NN
    const int lane = tid & 63;
    const unsigned info = noff[c];
    const int off = (int)(info & 0x1FFFFFu);
    const int dcap = (int)(info >> 21);

    float a0 = __bfloat162float(xsh[(size_t)c * 64 + lane]);  // self-loop term
    float a1 = 0.0f, a2 = 0.0f, a3 = 0.0f;
    if (dcap < 2047) {
        for (int base = 0; base < dcap; base += 64) {
            const int m = (dcap - base < 64) ? (dcap - base) : 64;
            const unsigned sv = (lane < m) ? packed[off + base + lane] : 0u;
            int j = 0;
            for (; j + 3 < m; j += 4) {  // uniform trip count, all lanes active
                const int s0 = (int)__shfl(sv, j);
                const int s1 = (int)__shfl(sv, j + 1);
                const int s2 = (int)__shfl(sv, j + 2);
                const int s3 = (int)__shfl(sv, j + 3);
                a0 += __bfloat162float(xsh[(size_t)s0 * 64 + lane]);
                a1 += __bfloat162float(xsh[(size_t)s1 * 64 + lane]);
                a2 += __bfloat162float(xsh[(size_t)s2 * 64 + lane]);
                a3 += __bfloat162float(xsh[(size_t)s3 * 64 + lane]);
            }
            for (; j < m; ++j) {  // uniform tail
                const int s0 = (int)__shfl(sv, j);
                a0 += __bfloat162float(xsh[(size_t)s0 * 64 + lane]);
            }
        }
    } else {  // scan-mode fallback (oversized bucket; segment still src|tl)
        const int b = c >> 6;
        int ss = bstart[b], ee = bstart[b + 1];
        if (ss < 0) ss = 0;
        if (ee > NE) ee = NE;
        const unsigned tl = (unsigned)(c & 63);
        for (int i = ss; i < ee; ++i) {
            const unsigned pk = packed[i];  // uniform address: broadcast load
            if ((pk >> 17) == tl)
                a0 += __bfloat162float(xsh[(size_t)(pk & 0x1FFFFu) * 64 + lane]);
        }
    }
    const float a = (a0 + a1) + (a2 + a3);
    const int p = c * 64 + lane;
    unsigned o0, o1;
    threefry2x32(0u, 42u, 0u, (unsigned)p, o0, o1);
    const unsigned bits = o0 ^ o1;
    const float u = __uint_as_float((bits >> 9) | 0x3f800000u) - 1.0f;
    const float h = tanhf(dinv[c] * a + bias[lane]);
    out[p] = (u < 0.9f) ? h / 0.9f : 0.0f;
}

extern "C" void kernel_launch(void* const* d_in, const int* in_sizes, int n_in,
                              void* d_out, int out_size, void* d_ws, size_t ws_size,
                              hipStream_t stream) {
    const float* x  = (const float*)d_in[0];
    const float* W  = (const float*)d_in[1];
    const float* b  = (const float*)d_in[2];
    const int*   ei = (const int*)d_in[3];
    float* out = (float*)d_out;

    float* dinv = (float*)d_ws;                             // f32[NN]
    __hip_bfloat16* xsh = (__hip_bfloat16*)(dinv + NN);     // bf16[NN*64]
    unsigned* packed = (unsigned*)(xsh + (size_t)NN * 64);  // u32[NE]
    unsigned* noff = packed + NE;                           // u32[NN]
    int* bhist  = (int*)(noff + NN);                        // i32[NBUCK]
    int* bstart = bhist + NBUCK;                            // i32[NBUCK+1]
    int* bcur   = bstart + NBUCK + 1;                       // i32[NBUCK]

    hipMemsetAsync(bhist, 0, NBUCK * sizeof(int), stream);
    k_bhist<<<P1B, 256, 0, stream>>>(ei, bhist);
    k_bscan<<<1, 1024, 0, stream>>>(bhist, bstart, bcur);
    k_p1<<<P1B, 256, 0, stream>>>(ei, bcur, packed);
    k_sortb<<<NBUCK, 256, 0, stream>>>(packed, bstart, dinv, noff);
    k_xw<<<(NN + 63) / 64, 256, 0, stream>>>(x, W, dinv, xsh);
    k_agg<<<NN / 4, 256, 0, stream>>>(packed, noff, bstart, xsh, dinv, b, out);
}

// Round 13
// 148.607 us; speedup vs baseline: 1.4786x; 1.2754x over previous
//
#include <hip/hip_runtime.h>
#include <hip/hip_bf16.h>

// GCNConv: coarse bin (64 tgts/bucket, grouped writes) -> per-bucket LDS
// counting sort to per-node CSR (in place over packed) -> per-node wave gather.
// agg[c] = dinv[c] * ( xs[c] + sum_{e: col[e]==c} xs[row[e]] ),
//   xs[i] = (x@W)[i] * dinv[i],  dinv[i] = rsqrt(1 + indeg(i))
// out = dropout(tanh(agg + b)), JAX partitionable-threefry key (0,42), p_keep=0.9:
//   bits[p] = o0^o1 of threefry((0,42), 0, p); u = bitcast(bits>>9|0x3f800000)-1; keep = u<0.9.
//
// R8: __shfl sources must be ACTIVE lanes — keep trip counts wave-uniform.
// R9: 128x256 binning was latency-starved; R12: 512x256 binning = 8x write amp
//   (runs of 2 edges). R13: 128x1024 — runs of ~8 edges (32B), amp ~2x.
// R12: k_agg was VALU-issue-heavy (57-62% busy). R13: paired-edge lanes —
//   one uint load = 2 bf16 dims, 2 edges per wave-instr, bf16->f32 via shift.
//
// ws (20.0 MB): dinv f32[NN] | xsh bf16[NN*64] | packed u32[NE] |
//               noff u32[NN] | bhist i32[NBUCK] | bstart i32[NBUCK+1] | bcur i32[NBUCK]

#define NN 100000
#define NE 1600000
#define NBUCK 1563
#define P1B 128
#define P1T 1024
#define CHUNK 12500         // P1B * CHUNK == NE
#define STAGE_CAP 2560      // > mean(1024) + 48 sigma; fallback if exceeded

// ---------------- Threefry2x32 (JAX-exact) ----------------
__device__ __forceinline__ unsigned rotl32(unsigned x, int r) {
    return (x << r) | (x >> (32 - r));
}

__device__ __forceinline__ void threefry2x32(unsigned k0, unsigned k1,
                                             unsigned x0, unsigned x1,
                                             unsigned& o0, unsigned& o1) {
    const unsigned ks0 = k0, ks1 = k1, ks2 = k0 ^ k1 ^ 0x1BD11BDAu;
    x0 += ks0; x1 += ks1;
    x0 += x1; x1 = rotl32(x1, 13); x1 ^= x0;
    x0 += x1; x1 = rotl32(x1, 15); x1 ^= x0;
    x0 += x1; x1 = rotl32(x1, 26); x1 ^= x0;
    x0 += x1; x1 = rotl32(x1, 6);  x1 ^= x0;
    x0 += ks1; x1 += ks2 + 1u;
    x0 += x1; x1 = rotl32(x1, 17); x1 ^= x0;
    x0 += x1; x1 = rotl32(x1, 29); x1 ^= x0;
    x0 += x1; x1 = rotl32(x1, 16); x1 ^= x0;
    x0 += x1; x1 = rotl32(x1, 24); x1 ^= x0;
    x0 += ks2; x1 += ks0 + 2u;
    x0 += x1; x1 = rotl32(x1, 13); x1 ^= x0;
    x0 += x1; x1 = rotl32(x1, 15); x1 ^= x0;
    x0 += x1; x1 = rotl32(x1, 26); x1 ^= x0;
    x0 += x1; x1 = rotl32(x1, 6);  x1 ^= x0;
    x0 += ks0; x1 += ks1 + 3u;
    x0 += x1; x1 = rotl32(x1, 17); x1 ^= x0;
    x0 += x1; x1 = rotl32(x1, 29); x1 ^= x0;
    x0 += x1; x1 = rotl32(x1, 16); x1 ^= x0;
    x0 += x1; x1 = rotl32(x1, 24); x1 ^= x0;
    x0 += ks1; x1 += ks2 + 4u;
    x0 += x1; x1 = rotl32(x1, 13); x1 ^= x0;
    x0 += x1; x1 = rotl32(x1, 15); x1 ^= x0;
    x0 += x1; x1 = rotl32(x1, 26); x1 ^= x0;
    x0 += x1; x1 = rotl32(x1, 6);  x1 ^= x0;
    x0 += ks2; x1 += ks0 + 5u;
    o0 = x0; o1 = x1;
}

// ---------------- Kernels ----------------
__global__ __launch_bounds__(P1T) void k_bhist(const int* __restrict__ ei,
                                               int* __restrict__ bhist) {
    __shared__ int h[NBUCK];
    const int tid = threadIdx.x;
    for (int i = tid; i < NBUCK; i += P1T) h[i] = 0;
    __syncthreads();
    const int base = blockIdx.x * CHUNK;
    for (int i = tid; i < CHUNK; i += P1T) {
        const unsigned t = (unsigned)ei[NE + base + i];
        if (t < NN) atomicAdd(&h[t >> 6], 1);
    }
    __syncthreads();
    for (int i = tid; i < NBUCK; i += P1T) {
        const int v = h[i];
        if (v) atomicAdd(&bhist[i], v);
    }
}

__global__ __launch_bounds__(1024) void k_bscan(const int* __restrict__ bhist,
                                                int* __restrict__ bstart,
                                                int* __restrict__ bcur) {
    __shared__ int s[2048];
    const int t = threadIdx.x;
    const int i0 = t, i1 = t + 1024;
    const int c0 = (i0 < NBUCK) ? bhist[i0] : 0;
    const int c1 = (i1 < NBUCK) ? bhist[i1] : 0;
    s[i0] = c0; s[i1] = c1;
    __syncthreads();
    for (int d = 1; d < 2048; d <<= 1) {
        const int a0 = (i0 >= d) ? s[i0 - d] : 0;
        const int a1 = (i1 >= d) ? s[i1 - d] : 0;
        __syncthreads();
        s[i0] += a0; s[i1] += a1;
        __syncthreads();
    }
    if (i0 < NBUCK) { const int b = s[i0] - c0; bstart[i0] = b; bcur[i0] = b; }
    if (i1 < NBUCK) { const int b = s[i1] - c1; bstart[i1] = b; bcur[i1] = b; }
    if (t == 0) bstart[NBUCK] = NE;
}

__global__ __launch_bounds__(P1T) void k_p1(const int* __restrict__ ei,
                                            int* __restrict__ bcur,
                                            unsigned* __restrict__ packed) {
    __shared__ int hb[NBUCK];
    __shared__ int lc[NBUCK];
    const int tid = threadIdx.x;
    for (int i = tid; i < NBUCK; i += P1T) { hb[i] = 0; lc[i] = 0; }
    __syncthreads();
    const int base = blockIdx.x * CHUNK;
    for (int i = tid; i < CHUNK; i += P1T) {
        const unsigned t = (unsigned)ei[NE + base + i];
        if (t < NN) atomicAdd(&hb[t >> 6], 1);
    }
    __syncthreads();
    for (int i = tid; i < NBUCK; i += P1T) {
        const int h = hb[i];
        hb[i] = h ? atomicAdd(&bcur[i], h) : 0;
    }
    __syncthreads();
    for (int i = tid; i < CHUNK; i += P1T) {
        const unsigned t = (unsigned)ei[NE + base + i];
        if (t >= NN) continue;
        const unsigned src = (unsigned)ei[base + i];
        const int bk = t >> 6;
        const unsigned pos = (unsigned)(hb[bk] + atomicAdd(&lc[bk], 1));
        if (pos < NE) packed[pos] = src | ((t & 63u) << 17);
    }
}

// Per-bucket: tl-histogram -> dinv + noff; LDS-stage + counting-sort the
// segment back over packed (node-grouped, tl stripped). Fallback: scan-mode.
__global__ __launch_bounds__(256) void k_sortb(unsigned* __restrict__ packed,
                                               const int* __restrict__ bstart,
                                               float* __restrict__ dinv,
                                               unsigned* __restrict__ noff) {
    __shared__ unsigned stage[STAGE_CAP];
    __shared__ int hist[64];
    __shared__ int pref[64];
    __shared__ int cur[64];
    const int tid = threadIdx.x;
    const int b = blockIdx.x;
    int s = bstart[b], e = bstart[b + 1];
    if (s < 0) s = 0;
    if (e > NE) e = NE;
    if (e < s) e = s;
    const int seg = e - s;
    if (tid < 64) hist[tid] = 0;
    __syncthreads();
    for (int i = s + tid; i < e; i += 256) atomicAdd(&hist[packed[i] >> 17], 1);
    __syncthreads();
    if (tid == 0) {
        int run = 0;
        for (int t = 0; t < 64; ++t) { pref[t] = run; run += hist[t]; }
    }
    __syncthreads();
    if (tid < 64) cur[tid] = pref[tid];
    const bool oversize = (seg > STAGE_CAP);
    if (tid < 64) {
        const int c = b * 64 + tid;
        if (c < NN) {
            const int deg = hist[tid];
            dinv[c] = rsqrtf(1.0f + (float)deg);
            const unsigned dcap = oversize ? 2047u
                                           : ((deg > 2046) ? 2047u : (unsigned)deg);
            noff[c] = (unsigned)(s + pref[tid]) | (dcap << 21);
        }
    }
    if (oversize) return;  // segment left in src|tl form; k_agg scans it
    __syncthreads();
    for (int i = s + tid; i < e; i += 256) stage[i - s] = packed[i];
    __syncthreads();
    for (int k = tid; k < seg; k += 256) {
        const unsigned pk = stage[k];
        const int tl = (int)(pk >> 17);
        const int pos = s + atomicAdd(&cur[tl], 1);
        packed[pos] = pk & 0x1FFFFu;
    }
}

// x@W: W register-resident, x rows staged in LDS, distributed per-row via
// ds_read_b128 broadcasts + 64 register FMAs. 64 rows/block, 16/wave.
__global__ __launch_bounds__(256) void k_xw(const float* __restrict__ x,
                                            const float* __restrict__ W,
                                            const float* __restrict__ dinv,
                                            __hip_bfloat16* __restrict__ xsh) {
    __shared__ float Wl[64 * 64];   // 16 KB
    __shared__ float xl[64 * 64];   // 16 KB
    const int tid = threadIdx.x;
    for (int i = tid; i < 64 * 64; i += 256) Wl[i] = W[i];  // coalesced
    const int row0 = blockIdx.x * 64;
    {
        const int nfl4 = ((NN - row0) < 64 ? (NN - row0) : 64) * 16;
        const float4* __restrict__ xg = (const float4*)(x + (size_t)row0 * 64);
        float4* __restrict__ xl4 = (float4*)xl;
        for (int i = tid; i < nfl4; i += 256) xl4[i] = xg[i];
    }
    __syncthreads();
    const int wid = tid >> 6, lane = tid & 63;
    float wreg[64];
#pragma unroll
    for (int k = 0; k < 64; ++k) wreg[k] = Wl[k * 64 + lane];
    const int rbase = wid * 16;
#pragma unroll 1
    for (int r = 0; r < 16; ++r) {
        const int row = row0 + rbase + r;
        if (row >= NN) break;  // wave-uniform
        const float4* __restrict__ xr4 = (const float4*)(xl + (rbase + r) * 64);
        float sum = 0.0f;
#pragma unroll
        for (int q = 0; q < 16; ++q) {
            const float4 xv = xr4[q];  // ds_read_b128 broadcast
            sum = fmaf(xv.x, wreg[4 * q + 0], sum);
            sum = fmaf(xv.y, wreg[4 * q + 1], sum);
            sum = fmaf(xv.z, wreg[4 * q + 2], sum);
            sum = fmaf(xv.w, wreg[4 * q + 3], sum);
        }
        xsh[(size_t)row * 64 + lane] = __float2bfloat16(sum * dinv[row]);
    }
}

// One wave per node, paired-edge lanes: g = lane>>5 selects edge parity,
// hl = lane&31 selects a bf16 PAIR (dims 2hl, 2hl+1) loaded as one uint.
// 2 edges per wave-instruction, 4 pair-chains in the main loop (8 edges in
// flight). All __shfl trip counts wave-uniform (R8); loads predicated on
// edge validity only. bf16->f32 via shift. Fused tanh+dropout epilogue.
__global__ __launch_bounds__(256) void k_agg(const unsigned* __restrict__ packed,
                                             const unsigned* __restrict__ noff,
                                             const int* __restrict__ bstart,
                                             const __hip_bfloat16* __restrict__ xsh,
                                             const float* __restrict__ dinv,
                                             const float* __restrict__ bias,
                                             float* __restrict__ out) {
    const int tid = threadIdx.x;
    const int c = blockIdx.x * 4 + (tid >> 6);  // grid exact: 25000*4 == NN
    const int lane = tid & 63, g = lane >> 5, hl = lane & 31;
    const unsigned info = noff[c];
    const int off = (int)(info & 0x1FFFFFu);
    const int dcap = (int)(info >> 21);
    const unsigned* __restrict__ xs2 = (const unsigned*)xsh;  // bf16 pairs

    float lo0 = 0.f, lo1 = 0.f, lo2 = 0.f, lo3 = 0.f;
    float hi0 = 0.f, hi1 = 0.f, hi2 = 0.f, hi3 = 0.f;
    if (g == 0) {  // self-loop term (counted once)
        const unsigned v = xs2[(size_t)c * 32 + hl];
        lo0 += __uint_as_float(v << 16);
        hi0 += __uint_as_float(v & 0xffff0000u);
    }
    if (dcap < 2047) {
        for (int base = 0; base < dcap; base += 64) {
            const int m = (dcap - base < 64) ? (dcap - base) : 64;
            const unsigned sv = (lane < m) ? packed[off + base + lane] : 0u;
            int j = 0;
            for (; j + 7 < m; j += 8) {  // 8 edges: 4 pair-chains, all valid
                const int s0 = (int)__shfl(sv, j + g);
                const int s1 = (int)__shfl(sv, j + 2 + g);
                const int s2 = (int)__shfl(sv, j + 4 + g);
                const int s3 = (int)__shfl(sv, j + 6 + g);
                const unsigned v0 = xs2[(size_t)s0 * 32 + hl];
                const unsigned v1 = xs2[(size_t)s1 * 32 + hl];
                const unsigned v2 = xs2[(size_t)s2 * 32 + hl];
                const unsigned v3 = xs2[(size_t)s3 * 32 + hl];
                lo0 += __uint_as_float(v0 << 16); hi0 += __uint_as_float(v0 & 0xffff0000u);
                lo1 += __uint_as_float(v1 << 16); hi1 += __uint_as_float(v1 & 0xffff0000u);
                lo2 += __uint_as_float(v2 << 16); hi2 += __uint_as_float(v2 & 0xffff0000u);
                lo3 += __uint_as_float(v3 << 16); hi3 += __uint_as_float(v3 & 0xffff0000u);
            }
            for (; j < m; j += 2) {  // tail pairs: shfl src e<=m (active lane)
                const int e = j + g;
                const int s0 = (int)__shfl(sv, e);
                if (e < m) {
                    const unsigned v = xs2[(size_t)s0 * 32 + hl];
                    lo0 += __uint_as_float(v << 16);
                    hi0 += __uint_as_float(v & 0xffff0000u);
                }
            }
        }
    } else {  // scan-mode fallback (oversized bucket; segment still src|tl)
        const int b = c >> 6;
        int ss = bstart[b], ee = bstart[b + 1];
        if (ss < 0) ss = 0;
        if (ee > NE) ee = NE;
        const unsigned tl = (unsigned)(c & 63);
        for (int i = ss; i < ee; ++i) {
            const unsigned pk = packed[i];  // uniform broadcast load
            if ((pk >> 17) == tl && g == 0) {
                const unsigned v = xs2[(size_t)(pk & 0x1FFFFu) * 32 + hl];
                lo0 += __uint_as_float(v << 16);
                hi0 += __uint_as_float(v & 0xffff0000u);
            }
        }
    }
    float alo = (lo0 + lo1) + (lo2 + lo3);
    float ahi = (hi0 + hi1) + (hi2 + hi3);
    alo += __shfl_xor(alo, 32);  // combine edge-parity halves
    ahi += __shfl_xor(ahi, 32);
    // redistribute: lane l takes dim l from lane l>>1 (uniform shfls)
    const float va = __shfl(alo, lane >> 1);
    const float vb = __shfl(ahi, lane >> 1);
    const float a = (lane & 1) ? vb : va;
    const int p = c * 64 + lane;
    unsigned o0, o1;
    threefry2x32(0u, 42u, 0u, (unsigned)p, o0, o1);
    const unsigned bits = o0 ^ o1;
    const float u = __uint_as_float((bits >> 9) | 0x3f800000u) - 1.0f;
    const float h = tanhf(dinv[c] * a + bias[lane]);
    out[p] = (u < 0.9f) ? h / 0.9f : 0.0f;
}

extern "C" void kernel_launch(void* const* d_in, const int* in_sizes, int n_in,
                              void* d_out, int out_size, void* d_ws, size_t ws_size,
                              hipStream_t stream) {
    const float* x  = (const float*)d_in[0];
    const float* W  = (const float*)d_in[1];
    const float* b  = (const float*)d_in[2];
    const int*   ei = (const int*)d_in[3];
    float* out = (float*)d_out;

    float* dinv = (float*)d_ws;                             // f32[NN]
    __hip_bfloat16* xsh = (__hip_bfloat16*)(dinv + NN);     // bf16[NN*64]
    unsigned* packed = (unsigned*)(xsh + (size_t)NN * 64);  // u32[NE]
    unsigned* noff = packed + NE;                           // u32[NN]
    int* bhist  = (int*)(noff + NN);                        // i32[NBUCK]
    int* bstart = bhist + NBUCK;                            // i32[NBUCK+1]
    int* bcur   = bstart + NBUCK + 1;                       // i32[NBUCK]

    hipMemsetAsync(bhist, 0, NBUCK * sizeof(int), stream);
    k_bhist<<<P1B, P1T, 0, stream>>>(ei, bhist);
    k_bscan<<<1, 1024, 0, stream>>>(bhist, bstart, bcur);
    k_p1<<<P1B, P1T, 0, stream>>>(ei, bcur, packed);
    k_sortb<<<NBUCK, 256, 0, stream>>>(packed, bstart, dinv, noff);
    k_xw<<<(NN + 63) / 64, 256, 0, stream>>>(x, W, dinv, xsh);
    k_agg<<<NN / 4, 256, 0, stream>>>(packed, noff, bstart, xsh, dinv, b, out);
}